// Round 1
// baseline (267.603 us; speedup 1.0000x reference)
//
#include <hip/hip_runtime.h>
#include <hip/hip_bf16.h>

#define N1 8192
#define N2 8192
#define CDIM 128
#define HC 60
#define WC 80
#define HIMG 480
#define WIMG 640
#define NPIX (HC * WC)
#define INV_DENOM (1.0f / (8192.0f * 256.0f))
#define T0BITS  0x4140u     // bf16 bits of 12.0 (positive range: bits monotone)
#define THIBITS 0x4200u     // bf16 bits of 32.0
#define PADK 136            // LDS row stride (128 + 8 ushort): keeps 16B align
#define CAP 1536            // per-row candidate list capacity (mean ~1182, +11 sigma)
#define CNTS 16             // per-row counter stride in ints (64B: own cacheline)

using bf16x8 = __attribute__((ext_vector_type(8))) short;
using f32x4  = __attribute__((ext_vector_type(4))) float;

__device__ __forceinline__ ushort f2bf(float f) {
    union { float f; unsigned u; } x; x.f = f;
    unsigned u = x.u;
    unsigned r = (u + 0x7FFFu + ((u >> 16) & 1u)) >> 16;
    return (ushort)r;
}
__device__ __forceinline__ float bf2f(unsigned bits) {
    union { unsigned u; float f; } x; x.u = bits << 16; return x.f;
}
__device__ __forceinline__ unsigned key2bits(unsigned k) {
    return k ^ ((k & 0x8000u) ? 0x8000u : 0xFFFFu);
}
__device__ __forceinline__ unsigned pair2key(unsigned x) {   // fallback only
    return x ^ 0x80008000u ^ (((x >> 15) & 0x00010001u) * 0x7FFFu);
}

// ---------- fused prep: cvt A, cvt B, transpose desc2, zero cand counters ----------
__global__ void prep_kernel(const float* __restrict__ kp1d,
                            const float* __restrict__ kp2d,
                            const float* __restrict__ desc2,
                            ushort* __restrict__ Abf, ushort* __restrict__ Bbf,
                            float* __restrict__ d2T, int* __restrict__ cnt) {
    const int n4 = N1 * CDIM / 4;        // 262144
    int i = blockIdx.x * blockDim.x + threadIdx.x;
    if (i < n4) {
        float4 v = ((const float4*)kp1d)[i];
        ushort4 o;
        o.x = f2bf(v.x); o.y = f2bf(v.y); o.z = f2bf(v.z); o.w = f2bf(v.w);
        ((ushort4*)Abf)[i] = o;
    } else if (i < 2 * n4) {
        int k = i - n4;
        float4 v = ((const float4*)kp2d)[k];
        ushort4 o;
        o.x = f2bf(v.x); o.y = f2bf(v.y); o.z = f2bf(v.z); o.w = f2bf(v.w);
        ((ushort4*)Bbf)[k] = o;
    } else {
        int e = i - 2 * n4;
        if (e < NPIX * CDIM) {
            int c = e / NPIX;
            int p = e - c * NPIX;
            d2T[(size_t)p * CDIM + c] = desc2[e];
        } else if (e < NPIX * CDIM + N1) {
            cnt[(size_t)(e - NPIX * CDIM) * CNTS] = 0;
        }
    }
}

// ---------- positive term (coalesced, plain store) ----------
__global__ void pos_kernel(const float* __restrict__ wkp1,
                           const float* __restrict__ kp1d,
                           const float* __restrict__ desc2T,
                           float* __restrict__ ploss) {
    const int i = blockIdx.x;
    const int c = threadIdx.x;            // 128 threads = 2 waves
    float y = wkp1[2 * i], x = wkp1[2 * i + 1];
    float py = fminf(fmaxf(y / (float)(HIMG - 1) * (float)(HC - 1), 0.0f), (float)(HC - 1));
    float px = fminf(fmaxf(x / (float)(WIMG - 1) * (float)(WC - 1), 0.0f), (float)(WC - 1));
    int y0 = min(max((int)floorf(py), 0), HC - 2);
    int x0 = min(max((int)floorf(px), 0), WC - 2);
    float wy = py - (float)y0;
    float wx = px - (float)x0;
    const int p00 = y0 * WC + x0;
    float v00 = desc2T[(size_t)p00 * CDIM + c];
    float v01 = desc2T[(size_t)(p00 + 1) * CDIM + c];
    float v10 = desc2T[(size_t)(p00 + WC) * CDIM + c];
    float v11 = desc2T[(size_t)(p00 + WC + 1) * CDIM + c];
    float v = v00 * (1.0f - wy) * (1.0f - wx) + v01 * (1.0f - wy) * wx
            + v10 * wy * (1.0f - wx) + v11 * wy * wx;
    float a = kp1d[(size_t)i * CDIM + c];
    float s2 = v * v, sav = a * v;
    #pragma unroll
    for (int off = 32; off >= 1; off >>= 1) {
        s2  += __shfl_down(s2, off);
        sav += __shfl_down(sav, off);
    }
    __shared__ float p2[2], pav[2];
    int wave = threadIdx.x >> 6, lane = threadIdx.x & 63;
    if (lane == 0) { p2[wave] = s2; pav[wave] = sav; }
    __syncthreads();
    if (threadIdx.x == 0) {
        float nrm = sqrtf(p2[0] + p2[1]);
        float pd = (pav[0] + pav[1]) / fmaxf(nrm, 1e-12f);
        float l = fmaxf(1.0f - pd, 0.0f) * (256.0f / 3.0f);
        ploss[i] = l * INV_DENOM;
    }
}

// ---------- masked GEMM + fused candidate compaction (R21) ----------
// R20 post-mortem: select_kernel's 53 us is the COMPACTION phase re-reading
// 64 MB of dots and re-testing every value the gemm epilogue already held in
// registers. R21: compact here. Per (mt,r) group: ballot the 4 candidate bits
// (value bits in (0x4141, 0x8000) i.e. > 12.0 after masking), per-quad-group
// popcount, one atomicAdd per row (64B-strided counters -> no cacheline
// ping-pong) to reserve a range, scatter bf16 bits into the per-row dense
// list. dots still written in full -- the exact fallback path needs it.
__global__ __launch_bounds__(256, 2)
void gemm_kernel(const ushort* __restrict__ A, const ushort* __restrict__ B,
                 const float* __restrict__ wkp1, const float* __restrict__ kp2,
                 ushort* __restrict__ dots, int* __restrict__ cnt,
                 ushort* __restrict__ cand, int m_off) {
    __shared__ ushort sA[128 * PADK];     // 34 KB
    __shared__ ushort sB[128 * PADK];     // 34 KB
    __shared__ float s_w[256], s_k[256];  // 2 KB coords

    const int t = threadIdx.x;
    const int n0 = blockIdx.x * 128;
    const int m0 = m_off + blockIdx.y * 128;

    s_w[t] = wkp1[2 * m0 + t];
    s_k[t] = kp2[2 * n0 + t];

    {
        const uint4* Ag = (const uint4*)(A + (size_t)m0 * CDIM);
        const uint4* Bg = (const uint4*)(B + (size_t)n0 * CDIM);
        #pragma unroll
        for (int r = 0; r < 8; r++) {
            int g = t + 256 * r;          // uint4 index 0..2047
            int row = g >> 4;
            int k8 = g & 15;
            uint4 va = Ag[g];
            uint4 vb = Bg[g];
            *(uint4*)(sA + row * PADK + k8 * 8) = va;
            *(uint4*)(sB + row * PADK + k8 * 8) = vb;
        }
    }
    __syncthreads();

    const int lane = t & 63;
    const int wave = t >> 6;
    const int wm = wave >> 1, wn = wave & 1;
    const int lrow = lane & 15, quad = lane >> 4;

    f32x4 acc[4][4];
    #pragma unroll
    for (int i = 0; i < 4; i++)
        #pragma unroll
        for (int j = 0; j < 4; j++) acc[i][j] = (f32x4){0.f, 0.f, 0.f, 0.f};

    #pragma unroll
    for (int kit = 0; kit < 4; kit++) {
        const int kk = kit * 32 + quad * 8;
        bf16x8 af[4], bfr[4];
        #pragma unroll
        for (int mt = 0; mt < 4; mt++)
            af[mt] = *(const bf16x8*)(sA + (wm * 64 + mt * 16 + lrow) * PADK + kk);
        #pragma unroll
        for (int nt = 0; nt < 4; nt++)
            bfr[nt] = *(const bf16x8*)(sB + (wn * 64 + nt * 16 + lrow) * PADK + kk);
        #pragma unroll
        for (int mt = 0; mt < 4; mt++)
            #pragma unroll
            for (int nt = 0; nt < 4; nt++)
                acc[mt][nt] = __builtin_amdgcn_mfma_f32_16x16x32_bf16(
                    af[mt], bfr[nt], acc[mt][nt], 0, 0, 0);
    }

    float ky[4], kx[4];
    #pragma unroll
    for (int nt = 0; nt < 4; nt++) {
        int jl = wn * 64 + nt * 16 + lrow;
        ky[nt] = s_k[2 * jl]; kx[nt] = s_k[2 * jl + 1];
    }
    const float thr = 2.0f * sqrtf(32.0f) + 0.1f;
    const float thr2 = thr * thr;
    const size_t colbase = (size_t)(n0 + wn * 64 + lrow * 4);
    const unsigned CSPAN = 0x8000u - 0x4141u;
    const unsigned lmask = (1u << lrow) - 1u;
    const int qsh = quad * 16;
    #pragma unroll
    for (int mt = 0; mt < 4; mt++) {
        #pragma unroll
        for (int r = 0; r < 4; r++) {
            const int il = wm * 64 + mt * 16 + quad * 4 + r;      // local row
            const int i = m0 + il;                                // global row
            const float wy = s_w[2 * il], wx = s_w[2 * il + 1];
            unsigned h[4];
            #pragma unroll
            for (int nt = 0; nt < 4; nt++) {
                float dy = wy - ky[nt], dx = wx - kx[nt];
                float v = acc[mt][nt][r];
                if (dy * dy + dx * dx <= thr2) v -= 5.0f;
                h[nt] = (unsigned)f2bf(v);
            }
            unsigned long long pk = (unsigned long long)(h[0] | (h[1] << 16))
                                  | ((unsigned long long)(h[2] | (h[3] << 16)) << 32);
            *(unsigned long long*)(dots + (size_t)(i - m_off) * N2 + colbase) = pk;

            // --- fused candidate compaction (same bit-domain test as select)
            bool c0 = (h[0] - 0x4141u) < CSPAN;
            bool c1 = (h[1] - 0x4141u) < CSPAN;
            bool c2 = (h[2] - 0x4141u) < CSPAN;
            bool c3 = (h[3] - 0x4141u) < CSPAN;
            unsigned gm0 = (unsigned)(__ballot(c0) >> qsh) & 0xFFFFu;
            unsigned gm1 = (unsigned)(__ballot(c1) >> qsh) & 0xFFFFu;
            unsigned gm2 = (unsigned)(__ballot(c2) >> qsh) & 0xFFFFu;
            unsigned gm3 = (unsigned)(__ballot(c3) >> qsh) & 0xFFFFu;
            int cc0 = __popc(gm0), cc1 = __popc(gm1), cc2 = __popc(gm2);
            int tot = cc0 + cc1 + cc2 + __popc(gm3);
            int base = 0;
            if (lrow == 0) base = atomicAdd(&cnt[(size_t)i * CNTS], tot);
            base = __shfl(base, qsh);        // lane 16*quad holds this row's base
            ushort* cp = cand + (size_t)i * CAP;
            int o0 = base + __popc(gm0 & lmask);
            int o1 = base + cc0 + __popc(gm1 & lmask);
            int o2 = base + cc0 + cc1 + __popc(gm2 & lmask);
            int o3 = base + cc0 + cc1 + cc2 + __popc(gm3 & lmask);
            if (c0 && o0 < CAP) cp[o0] = (ushort)h[0];
            if (c1 && o1 < CAP) cp[o1] = (ushort)h[1];
            if (c2 && o2 < CAP) cp[o2] = (ushort)h[2];
            if (c3 && o3 < CAP) cp[o3] = (ushort)h[3];
        }
    }
}

// ---------- per-row top-256 hinge sum from pre-compacted candidate lists ----------
// R21: one wave per row, no LDS, no barriers. Load cnt + the dense candidate
// list (<= 1536 bf16 values, ~2.4 KB, L2-resident) into 12 regs/lane, then the
// same 8-step bf16-bit bisect + hinge sum fully in registers. Hinge sum in
// DOUBLE: candidate terms are f32 with exponents 2^3..2^6, <=1536 of them sum
// exactly in f64 -> result is independent of the (nondeterministic) atomic
// append order. Fallback (cnt<256 | cnt>CAP | >255 values above 32.0): exact
// full-range key-domain bisect over the still-materialized dots row.
__global__ __launch_bounds__(256)
void select_kernel(const ushort* __restrict__ dots,
                   const int* __restrict__ cnt,
                   const ushort* __restrict__ cand,
                   float* __restrict__ rloss, int m_off) {
    const int wave = threadIdx.x >> 6;     // 0..3
    const int lane = threadIdx.x & 63;
    const int g = m_off + blockIdx.x * 4 + wave;   // global row

    const int craw = cnt[(size_t)g * CNTS];
    const int len = min(craw, CAP);
    const unsigned* lp = (const unsigned*)(cand + (size_t)g * CAP);

    unsigned v[CAP / 128];                 // 12 uints = 24 candidates/lane
    #pragma unroll
    for (int u = 0; u < CAP / 128; u++) {
        int p = u * 64 + lane;
        unsigned x = lp[p];                // in-capacity read; garbage masked below
        x = (2 * p + 1 < len) ? x : ((2 * p < len) ? (x & 0xFFFFu) : 0u);
        v[u] = x;
    }

    int th = 0;                            // count of values > 32.0
    #pragma unroll
    for (int u = 0; u < CAP / 128; u++)
        th += (int)((v[u] & 0xFFFFu) > THIBITS) + (int)((v[u] >> 16) > THIBITS);
    #pragma unroll
    for (int off = 32; off >= 1; off >>= 1) th += __shfl_down(th, off);
    th = __shfl(th, 0);

    const bool ok = (craw >= 256) && (craw <= CAP) && (th <= 255);

    unsigned ktb;           // bf16 bits of 256th-largest (attained)
    double s = 0.0; int cgt = 0;

    if (ok) {
        // ---- bisect raw bits over (T0BITS, THIBITS]: 8 iterations, in-register
        int lo = (int)T0BITS, hi = (int)THIBITS;
        while (hi - lo > 1) {
            const unsigned mid = (unsigned)((lo + hi) >> 1);
            int c = 0;
            #pragma unroll
            for (int u = 0; u < CAP / 128; u++)
                c += (int)((v[u] & 0xFFFFu) > mid) + (int)((v[u] >> 16) > mid);
            #pragma unroll
            for (int off = 32; off >= 1; off >>= 1) c += __shfl_down(c, off);
            c = __shfl(c, 0);
            if (c >= 256) lo = (int)mid; else hi = (int)mid;
        }
        ktb = (unsigned)hi;
        #pragma unroll
        for (int u = 0; u < CAP / 128; u++) {
            unsigned h0 = v[u] & 0xFFFFu, h1 = v[u] >> 16;
            if (h0 > ktb) { s += (double)(bf2f(h0) - 0.2f); cgt++; }
            if (h1 > ktb) { s += (double)(bf2f(h1) - 0.2f); cgt++; }
        }
    } else {
        // ---- exact fallback: full-range key-domain bisect from global (full row)
        const uint4* rp4 = (const uint4*)(dots + (size_t)(g - m_off) * N2);
        int lo = -1, hi = 65535;
        while (hi - lo > 1) {
            unsigned midu = (unsigned)((lo + hi) >> 1);
            unsigned midhi = (midu << 16) | 0xFFFFu;
            int c = 0;
            for (int j = 0; j < 16; j++) {
                uint4 w = rp4[lane + 64 * j];
                unsigned xs[4] = {w.x, w.y, w.z, w.w};
                #pragma unroll
                for (int u = 0; u < 4; u++) {
                    unsigned kk = pair2key(xs[u]);
                    c += (int)((kk & 0xFFFFu) > midu) + (int)(kk > midhi);
                }
            }
            #pragma unroll
            for (int off = 32; off >= 1; off >>= 1) c += __shfl_down(c, off);
            c = __shfl(c, 0);
            if (c >= 256) lo = (int)midu; else hi = (int)midu;
        }
        unsigned kt = (unsigned)hi;
        const unsigned kthi = (kt << 16) | 0xFFFFu;
        for (int j = 0; j < 16; j++) {
            uint4 w = rp4[lane + 64 * j];
            unsigned xs[4] = {w.x, w.y, w.z, w.w};
            #pragma unroll
            for (int u = 0; u < 4; u++) {
                unsigned kk = pair2key(xs[u]);
                unsigned lowk = kk & 0xFFFFu, highk = kk >> 16;
                if (lowk > kt) { s += (double)fmaxf(bf2f(key2bits(lowk))  - 0.2f, 0.f); cgt++; }
                if (kk > kthi) { s += (double)fmaxf(bf2f(key2bits(highk)) - 0.2f, 0.f); cgt++; }
            }
        }
        ktb = key2bits(kt);
    }

    #pragma unroll
    for (int off = 32; off >= 1; off >>= 1) {
        s += __shfl_down(s, off);
        cgt += __shfl_down(cgt, off);
    }
    if (lane == 0) {
        float vt = bf2f(ktb);
        double S = s + (double)(256 - cgt) * (double)fmaxf(vt - 0.2f, 0.0f);
        rloss[g] = (float)(S * (double)INV_DENOM);
    }
}

// ---------- final reduce: sum 2*N1 floats -> out[0] ----------
__global__ void reduce_kernel(const float* __restrict__ a, float* __restrict__ out) {
    const int t = threadIdx.x;
    float s = 0.f;
    for (int i = t; i < 2 * N1; i += 256) s += a[i];
    #pragma unroll
    for (int off = 32; off >= 1; off >>= 1) s += __shfl_down(s, off);
    __shared__ float ws[4];
    int wave = t >> 6, lane = t & 63;
    if (lane == 0) ws[wave] = s;
    __syncthreads();
    if (t == 0) out[0] = ws[0] + ws[1] + ws[2] + ws[3];
}

extern "C" void kernel_launch(void* const* d_in, const int* in_sizes, int n_in,
                              void* d_out, int out_size, void* d_ws, size_t ws_size,
                              hipStream_t stream) {
    const float* wkp1  = (const float*)d_in[1];
    const float* kp2   = (const float*)d_in[2];
    const float* kp1d  = (const float*)d_in[3];
    const float* kp2d  = (const float*)d_in[4];
    const float* desc2 = (const float*)d_in[5];
    float* out = (float*)d_out;

    ushort* Abf   = (ushort*)d_ws;                         // 2 MB
    ushort* Bbf   = Abf + (size_t)N1 * CDIM;               // 2 MB
    float*  loss  = (float*)(Bbf + (size_t)N2 * CDIM);     // 64 KB (pos | rows)
    float*  d2T   = loss + 2 * N1;                         // 2.4 MB
    int*    cnt   = (int*)(d2T + (size_t)NPIX * CDIM);     // 512 KB (64B/row)
    ushort* cand  = (ushort*)(cnt + (size_t)N1 * CNTS);    // 24 MB cand lists
    ushort* dots  = cand + (size_t)N1 * CAP;               // chunked dots

    size_t head_bytes = (size_t)(N1 + N2) * CDIM * sizeof(ushort)
                      + 2 * N1 * sizeof(float)
                      + (size_t)NPIX * CDIM * sizeof(float)
                      + (size_t)N1 * CNTS * sizeof(int)
                      + (size_t)N1 * CAP * sizeof(ushort);
    size_t avail = (ws_size > head_bytes) ? (ws_size - head_bytes) : 0;
    long rows_chunk = (long)(avail / ((size_t)N2 * sizeof(ushort)));
    rows_chunk = (rows_chunk / 128) * 128;
    if (rows_chunk > N1) rows_chunk = N1;
    if (rows_chunk < 128) rows_chunk = 128;      // requires ws >= ~35 MB

    int n4 = N1 * CDIM / 4;
    int prep_elems = 2 * n4 + NPIX * CDIM + N1;
    prep_kernel<<<(prep_elems + 255) / 256, 256, 0, stream>>>(kp1d, kp2d, desc2,
                                                              Abf, Bbf, d2T, cnt);

    pos_kernel<<<N1, 128, 0, stream>>>(wkp1, kp1d, d2T, loss);

    for (int r0 = 0; r0 < N1; r0 += (int)rows_chunk) {
        int rows = (int)((N1 - r0 < rows_chunk) ? (N1 - r0) : rows_chunk);
        dim3 grid(N2 / 128, rows / 128);
        gemm_kernel<<<grid, 256, 0, stream>>>(Abf, Bbf, wkp1, kp2, dots, cnt, cand, r0);
        select_kernel<<<rows / 4, 256, 0, stream>>>(dots, cnt, cand, loss + N1, r0);
    }

    reduce_kernel<<<1, 256, 0, stream>>>(loss, out);
}

// Round 2
// 162.896 us; speedup vs baseline: 1.6428x; 1.6428x over previous
//
#include <hip/hip_runtime.h>
#include <hip/hip_bf16.h>

#define N1 8192
#define N2 8192
#define CDIM 128
#define HC 60
#define WC 80
#define HIMG 480
#define WIMG 640
#define NPIX (HC * WC)
#define INV_DENOM (1.0f / (8192.0f * 256.0f))
#define T0BITS  0x4140u     // bf16 bits of 12.0 (positive range: bits monotone)
#define THIBITS 0x4200u     // bf16 bits of 32.0
#define PADK 136            // LDS row stride (128 + 8 ushort): keeps 16B align

using bf16x8 = __attribute__((ext_vector_type(8))) short;
using f32x4  = __attribute__((ext_vector_type(4))) float;

__device__ __forceinline__ ushort f2bf(float f) {
    union { float f; unsigned u; } x; x.f = f;
    unsigned u = x.u;
    unsigned r = (u + 0x7FFFu + ((u >> 16) & 1u)) >> 16;
    return (ushort)r;
}
__device__ __forceinline__ float bf2f(unsigned bits) {
    union { unsigned u; float f; } x; x.u = bits << 16; return x.f;
}
__device__ __forceinline__ unsigned key2bits(unsigned k) {
    return k ^ ((k & 0x8000u) ? 0x8000u : 0xFFFFu);
}
__device__ __forceinline__ unsigned pair2key(unsigned x) {   // fallback only
    return x ^ 0x80008000u ^ (((x >> 15) & 0x00010001u) * 0x7FFFu);
}

// ---------- fused prep: cvt A, cvt B, transpose desc2 ----------
__global__ void prep_kernel(const float* __restrict__ kp1d,
                            const float* __restrict__ kp2d,
                            const float* __restrict__ desc2,
                            ushort* __restrict__ Abf, ushort* __restrict__ Bbf,
                            float* __restrict__ d2T) {
    const int n4 = N1 * CDIM / 4;        // 262144
    int i = blockIdx.x * blockDim.x + threadIdx.x;
    if (i < n4) {
        float4 v = ((const float4*)kp1d)[i];
        ushort4 o;
        o.x = f2bf(v.x); o.y = f2bf(v.y); o.z = f2bf(v.z); o.w = f2bf(v.w);
        ((ushort4*)Abf)[i] = o;
    } else if (i < 2 * n4) {
        int k = i - n4;
        float4 v = ((const float4*)kp2d)[k];
        ushort4 o;
        o.x = f2bf(v.x); o.y = f2bf(v.y); o.z = f2bf(v.z); o.w = f2bf(v.w);
        ((ushort4*)Bbf)[k] = o;
    } else {
        int e = i - 2 * n4;
        if (e < NPIX * CDIM) {
            int c = e / NPIX;
            int p = e - c * NPIX;
            d2T[(size_t)p * CDIM + c] = desc2[e];
        }
    }
}

// ---------- positive term (coalesced, plain store) ----------
__global__ void pos_kernel(const float* __restrict__ wkp1,
                           const float* __restrict__ kp1d,
                           const float* __restrict__ desc2T,
                           float* __restrict__ ploss) {
    const int i = blockIdx.x;
    const int c = threadIdx.x;            // 128 threads = 2 waves
    float y = wkp1[2 * i], x = wkp1[2 * i + 1];
    float py = fminf(fmaxf(y / (float)(HIMG - 1) * (float)(HC - 1), 0.0f), (float)(HC - 1));
    float px = fminf(fmaxf(x / (float)(WIMG - 1) * (float)(WC - 1), 0.0f), (float)(WC - 1));
    int y0 = min(max((int)floorf(py), 0), HC - 2);
    int x0 = min(max((int)floorf(px), 0), WC - 2);
    float wy = py - (float)y0;
    float wx = px - (float)x0;
    const int p00 = y0 * WC + x0;
    float v00 = desc2T[(size_t)p00 * CDIM + c];
    float v01 = desc2T[(size_t)(p00 + 1) * CDIM + c];
    float v10 = desc2T[(size_t)(p00 + WC) * CDIM + c];
    float v11 = desc2T[(size_t)(p00 + WC + 1) * CDIM + c];
    float v = v00 * (1.0f - wy) * (1.0f - wx) + v01 * (1.0f - wy) * wx
            + v10 * wy * (1.0f - wx) + v11 * wy * wx;
    float a = kp1d[(size_t)i * CDIM + c];
    float s2 = v * v, sav = a * v;
    #pragma unroll
    for (int off = 32; off >= 1; off >>= 1) {
        s2  += __shfl_down(s2, off);
        sav += __shfl_down(sav, off);
    }
    __shared__ float p2[2], pav[2];
    int wave = threadIdx.x >> 6, lane = threadIdx.x & 63;
    if (lane == 0) { p2[wave] = s2; pav[wave] = sav; }
    __syncthreads();
    if (threadIdx.x == 0) {
        float nrm = sqrtf(p2[0] + p2[1]);
        float pd = (pav[0] + pav[1]) / fmaxf(nrm, 1e-12f);
        float l = fmaxf(1.0f - pd, 0.0f) * (256.0f / 3.0f);
        ploss[i] = l * INV_DENOM;
    }
}

// ---------- masked GEMM, LDS-staged, packed permuted stores (R0-exact revert) ----------
// R1 post-mortem: in-gemm global-atomic candidate append cost +80us (atomic
// round-trip stalls, cross-XCD cand-line writeback inflation +70MB). Reverted.
__global__ __launch_bounds__(256, 2)
void gemm_kernel(const ushort* __restrict__ A, const ushort* __restrict__ B,
                 const float* __restrict__ wkp1, const float* __restrict__ kp2,
                 ushort* __restrict__ dots, int m_off) {
    __shared__ ushort sA[128 * PADK];     // 34 KB
    __shared__ ushort sB[128 * PADK];     // 34 KB
    __shared__ float s_w[256], s_k[256];  // 2 KB coords

    const int t = threadIdx.x;
    const int n0 = blockIdx.x * 128;
    const int m0 = m_off + blockIdx.y * 128;

    s_w[t] = wkp1[2 * m0 + t];
    s_k[t] = kp2[2 * n0 + t];

    {
        const uint4* Ag = (const uint4*)(A + (size_t)m0 * CDIM);
        const uint4* Bg = (const uint4*)(B + (size_t)n0 * CDIM);
        #pragma unroll
        for (int r = 0; r < 8; r++) {
            int g = t + 256 * r;          // uint4 index 0..2047
            int row = g >> 4;
            int k8 = g & 15;
            uint4 va = Ag[g];
            uint4 vb = Bg[g];
            *(uint4*)(sA + row * PADK + k8 * 8) = va;
            *(uint4*)(sB + row * PADK + k8 * 8) = vb;
        }
    }
    __syncthreads();

    const int lane = t & 63;
    const int wave = t >> 6;
    const int wm = wave >> 1, wn = wave & 1;
    const int lrow = lane & 15, quad = lane >> 4;

    f32x4 acc[4][4];
    #pragma unroll
    for (int i = 0; i < 4; i++)
        #pragma unroll
        for (int j = 0; j < 4; j++) acc[i][j] = (f32x4){0.f, 0.f, 0.f, 0.f};

    #pragma unroll
    for (int kit = 0; kit < 4; kit++) {
        const int kk = kit * 32 + quad * 8;
        bf16x8 af[4], bfr[4];
        #pragma unroll
        for (int mt = 0; mt < 4; mt++)
            af[mt] = *(const bf16x8*)(sA + (wm * 64 + mt * 16 + lrow) * PADK + kk);
        #pragma unroll
        for (int nt = 0; nt < 4; nt++)
            bfr[nt] = *(const bf16x8*)(sB + (wn * 64 + nt * 16 + lrow) * PADK + kk);
        #pragma unroll
        for (int mt = 0; mt < 4; mt++)
            #pragma unroll
            for (int nt = 0; nt < 4; nt++)
                acc[mt][nt] = __builtin_amdgcn_mfma_f32_16x16x32_bf16(
                    af[mt], bfr[nt], acc[mt][nt], 0, 0, 0);
    }

    float ky[4], kx[4];
    #pragma unroll
    for (int nt = 0; nt < 4; nt++) {
        int jl = wn * 64 + nt * 16 + lrow;
        ky[nt] = s_k[2 * jl]; kx[nt] = s_k[2 * jl + 1];
    }
    const float thr = 2.0f * sqrtf(32.0f) + 0.1f;
    const float thr2 = thr * thr;
    const size_t colbase = (size_t)(n0 + wn * 64 + lrow * 4);
    #pragma unroll
    for (int mt = 0; mt < 4; mt++) {
        #pragma unroll
        for (int r = 0; r < 4; r++) {
            const int il = wm * 64 + mt * 16 + quad * 4 + r;      // local row
            const int i = m0 + il;
            const float wy = s_w[2 * il], wx = s_w[2 * il + 1];
            unsigned h[4];
            #pragma unroll
            for (int nt = 0; nt < 4; nt++) {
                float dy = wy - ky[nt], dx = wx - kx[nt];
                float v = acc[mt][nt][r];
                if (dy * dy + dx * dx <= thr2) v -= 5.0f;
                h[nt] = (unsigned)f2bf(v);
            }
            unsigned long long pk = (unsigned long long)(h[0] | (h[1] << 16))
                                  | ((unsigned long long)(h[2] | (h[3] << 16)) << 32);
            *(unsigned long long*)(dots + (size_t)(i - m_off) * N2 + colbase) = pk;
        }
    }
}

// ---------- per-row top-256 hinge via 192-bin bf16 HISTOGRAM (R2) ----------
// Key insight: the threshold domain (12.0, 32.0] contains only 192 distinct
// bf16 bit patterns. One block per row, 4 waves: each value does ONE ds_add
// into hist[min(h-0x4141, 192)] (dummy-slot cndmask for non-candidates -- no
// ballot/mbcnt/exec juggling, no 8-iter bisect re-reads). Bin 192 counts
// values > 32; their exact bits go to a small append list behind a per-uint4
// __any gate (~0.25% of values). Selection: wave0 suffix-scans 192 bins
// (6 shfl steps), finds minimal t with count(>t) < 256 == bisect's ktb, sums
// cnt[b]*(f32)(val(b)-0.2f) in f64 (== repeated addition of the identical f32
// terms -> bit-compatible with prior kernel; deterministic despite
// nondeterministic hi-append order since f64 sums <=255 such terms exactly).
// Fallback (tot<256 | nhi>255): exact full-range key-domain bisect over the
// still-materialized dots row (verbatim from prior passing kernel).
__global__ __launch_bounds__(256)
void select_kernel(const ushort* __restrict__ dots, float* __restrict__ rloss,
                   int m_off) {
    const int g = m_off + blockIdx.x;            // global row
    const int t = threadIdx.x;
    const int lane = t & 63;

    __shared__ unsigned hist[193];
    __shared__ unsigned dmy[64];
    __shared__ unsigned hicnt;
    __shared__ ushort hlist[256];

    if (t < 193) hist[t] = 0u;
    if (t == 0) hicnt = 0u;
    __syncthreads();

    const uint4* rp4 = (const uint4*)(dots + (size_t)(g - m_off) * N2);  // 1024 uint4

    // ---- pass 1: histogram build (all 4 waves), 4 uint4 per thread
    #pragma unroll
    for (int j = 0; j < 4; j++) {
        uint4 w = rp4[t + 256 * j];
        unsigned xs[4] = {w.x, w.y, w.z, w.w};
        bool anyhi = false;
        #pragma unroll
        for (int q = 0; q < 4; q++) {
            unsigned lo = xs[q] & 0xFFFFu, hh = xs[q] >> 16;
            unsigned u0 = lo - 0x4141u, u1 = hh - 0x4141u;   // candidate iff < 0x3EBF
            unsigned b0 = min(u0, 192u), b1 = min(u1, 192u);
            unsigned* p0 = (u0 < 0x3EBFu) ? &hist[b0] : &dmy[lane];
            unsigned* p1 = (u1 < 0x3EBFu) ? &hist[b1] : &dmy[lane];
            atomicAdd(p0, 1u);
            atomicAdd(p1, 1u);
            anyhi |= ((u0 - 0xC0u) < 0x3DFFu) | ((u1 - 0xC0u) < 0x3DFFu);
        }
        if (__any(anyhi)) {                       // rare: values > 32.0
            #pragma unroll
            for (int q = 0; q < 4; q++) {
                unsigned lo = xs[q] & 0xFFFFu, hh = xs[q] >> 16;
                unsigned u0 = lo - 0x4141u, u1 = hh - 0x4141u;
                if ((u0 - 0xC0u) < 0x3DFFu) {
                    unsigned id = atomicAdd(&hicnt, 1u);
                    if (id < 255u) hlist[id] = (ushort)lo;
                }
                if ((u1 - 0xC0u) < 0x3DFFu) {
                    unsigned id = atomicAdd(&hicnt, 1u);
                    if (id < 255u) hlist[id] = (ushort)hh;
                }
            }
        }
    }
    __syncthreads();
    if (t >= 64) return;                          // wave0 selects; no barriers follow

    const int l = lane;
    unsigned c0 = hist[l], c1 = hist[64 + l], c2 = hist[128 + l];
    const unsigned nhi = hist[192];

    // inclusive suffix-scan across lanes for each 64-bin chunk
    unsigned s0i = c0, s1i = c1, s2i = c2;
    #pragma unroll
    for (int off = 1; off < 64; off <<= 1) {
        unsigned t0 = __shfl_down(s0i, off);
        unsigned t1 = __shfl_down(s1i, off);
        unsigned t2 = __shfl_down(s2i, off);
        if (l + off < 64) { s0i += t0; s1i += t1; s2i += t2; }
    }
    const unsigned T0 = __shfl(s0i, 0), T1 = __shfl(s1i, 0), T2 = __shfl(s2i, 0);
    const unsigned tot = nhi + T0 + T1 + T2;      // count of values > 12.0 (=totLow)

    // count of values STRICTLY greater than this lane's bin value
    const unsigned Ce0 = nhi + T1 + T2 + (s0i - c0);
    const unsigned Ce1 = nhi + T2 + (s1i - c1);
    const unsigned Ce2 = nhi + (s2i - c2);

    const bool ok = (tot >= 256u) && (nhi <= 255u);

    unsigned ktb;            // bf16 bits of 256th-largest (attained)
    double s = 0.0;
    int cgt = 0;

    if (ok) {
        unsigned long long m0 = __ballot(Ce0 < 256u);
        unsigned long long m1 = __ballot(Ce1 < 256u);
        unsigned long long m2 = __ballot(Ce2 < 256u);
        int bmin; unsigned cg;
        if (m0) { int fl = __ffsll((unsigned long long)m0) - 1; bmin = fl;       cg = __shfl(Ce0, fl); }
        else if (m1) { int fl = __ffsll((unsigned long long)m1) - 1; bmin = 64 + fl;  cg = __shfl(Ce1, fl); }
        else { int fl = __ffsll((unsigned long long)m2) - 1; bmin = 128 + fl; cg = __shfl(Ce2, fl); }
        ktb = 0x4141u + (unsigned)bmin;
        cgt = (int)cg;
        // per-bin hinge sums: cnt * (f32)(val - 0.2f), exact in f64
        if (l > bmin)       s += (double)c0 * (double)(bf2f(0x4141u + (unsigned)l) - 0.2f);
        if (64 + l > bmin)  s += (double)c1 * (double)(bf2f(0x4141u + 64u + (unsigned)l) - 0.2f);
        if (128 + l > bmin) s += (double)c2 * (double)(bf2f(0x4141u + 128u + (unsigned)l) - 0.2f);
        // values > 32.0 (all above threshold; counted inside Ce via nhi)
        for (unsigned p = (unsigned)l; p < nhi; p += 64u)
            s += (double)(bf2f(hlist[p]) - 0.2f);
        // fold per-lane f64 partials
        #pragma unroll
        for (int off = 32; off >= 1; off >>= 1) s += __shfl_down(s, off);
    } else {
        // ---- exact fallback: full-range key-domain bisect from global (full row)
        int lo = -1, hi = 65535;
        while (hi - lo > 1) {
            unsigned midu = (unsigned)((lo + hi) >> 1);
            unsigned midhi = (midu << 16) | 0xFFFFu;
            int c = 0;
            for (int j = 0; j < 16; j++) {
                uint4 w = rp4[l + 64 * j];
                unsigned xs[4] = {w.x, w.y, w.z, w.w};
                #pragma unroll
                for (int u = 0; u < 4; u++) {
                    unsigned kk = pair2key(xs[u]);
                    c += (int)((kk & 0xFFFFu) > midu) + (int)(kk > midhi);
                }
            }
            #pragma unroll
            for (int off = 32; off >= 1; off >>= 1) c += __shfl_down(c, off);
            c = __shfl(c, 0);
            if (c >= 256) lo = (int)midu; else hi = (int)midu;
        }
        unsigned kt = (unsigned)hi;
        const unsigned kthi = (kt << 16) | 0xFFFFu;
        for (int j = 0; j < 16; j++) {
            uint4 w = rp4[l + 64 * j];
            unsigned xs[4] = {w.x, w.y, w.z, w.w};
            #pragma unroll
            for (int u = 0; u < 4; u++) {
                unsigned kk = pair2key(xs[u]);
                unsigned lowk = kk & 0xFFFFu, highk = kk >> 16;
                if (lowk > kt) { s += (double)fmaxf(bf2f(key2bits(lowk))  - 0.2f, 0.f); cgt++; }
                if (kk > kthi) { s += (double)fmaxf(bf2f(key2bits(highk)) - 0.2f, 0.f); cgt++; }
            }
        }
        ktb = key2bits(kt);
        #pragma unroll
        for (int off = 32; off >= 1; off >>= 1) {
            s += __shfl_down(s, off);
            cgt += __shfl_down(cgt, off);
        }
    }

    if (l == 0) {
        float vt = bf2f(ktb);
        double S = s + (double)(256 - cgt) * (double)fmaxf(vt - 0.2f, 0.0f);
        rloss[g] = (float)(S * (double)INV_DENOM);
    }
}

// ---------- final reduce: sum 2*N1 floats -> out[0] ----------
__global__ void reduce_kernel(const float* __restrict__ a, float* __restrict__ out) {
    const int t = threadIdx.x;
    float s = 0.f;
    for (int i = t; i < 2 * N1; i += 256) s += a[i];
    #pragma unroll
    for (int off = 32; off >= 1; off >>= 1) s += __shfl_down(s, off);
    __shared__ float ws[4];
    int wave = t >> 6, lane = t & 63;
    if (lane == 0) ws[wave] = s;
    __syncthreads();
    if (t == 0) out[0] = ws[0] + ws[1] + ws[2] + ws[3];
}

extern "C" void kernel_launch(void* const* d_in, const int* in_sizes, int n_in,
                              void* d_out, int out_size, void* d_ws, size_t ws_size,
                              hipStream_t stream) {
    const float* wkp1  = (const float*)d_in[1];
    const float* kp2   = (const float*)d_in[2];
    const float* kp1d  = (const float*)d_in[3];
    const float* kp2d  = (const float*)d_in[4];
    const float* desc2 = (const float*)d_in[5];
    float* out = (float*)d_out;

    ushort* Abf   = (ushort*)d_ws;                         // 2 MB
    ushort* Bbf   = Abf + (size_t)N1 * CDIM;               // 2 MB
    float*  loss  = (float*)(Bbf + (size_t)N2 * CDIM);     // 64 KB (pos | rows)
    float*  d2T   = loss + 2 * N1;                         // 2.4 MB
    ushort* dots  = (ushort*)(d2T + (size_t)NPIX * CDIM);  // chunked dots

    size_t head_bytes = (size_t)(N1 + N2) * CDIM * sizeof(ushort)
                      + 2 * N1 * sizeof(float)
                      + (size_t)NPIX * CDIM * sizeof(float);
    size_t avail = (ws_size > head_bytes) ? (ws_size - head_bytes) : 0;
    long rows_chunk = (long)(avail / ((size_t)N2 * sizeof(ushort)));
    rows_chunk = (rows_chunk / 128) * 128;
    if (rows_chunk > N1) rows_chunk = N1;
    if (rows_chunk < 128) rows_chunk = 128;      // requires ws >= ~9 MB

    int n4 = N1 * CDIM / 4;
    int prep_elems = 2 * n4 + NPIX * CDIM;
    prep_kernel<<<(prep_elems + 255) / 256, 256, 0, stream>>>(kp1d, kp2d, desc2,
                                                              Abf, Bbf, d2T);

    pos_kernel<<<N1, 128, 0, stream>>>(wkp1, kp1d, d2T, loss);

    for (int r0 = 0; r0 < N1; r0 += (int)rows_chunk) {
        int rows = (int)((N1 - r0 < rows_chunk) ? (N1 - r0) : rows_chunk);
        dim3 grid(N2 / 128, rows / 128);
        gemm_kernel<<<grid, 256, 0, stream>>>(Abf, Bbf, wkp1, kp2, dots, r0);
        select_kernel<<<rows, 256, 0, stream>>>(dots, loss + N1, r0);
    }

    reduce_kernel<<<1, 256, 0, stream>>>(loss, out);
}